// Round 1
// baseline (345.377 us; speedup 1.0000x reference)
//
#include <hip/hip_runtime.h>
#include <stdint.h>

#define SEQ 2048
#define C3 3072
#define C1 1024

typedef __bf16 bf16x8 __attribute__((ext_vector_type(8)));
typedef short short8 __attribute__((ext_vector_type(8)));
typedef float f32x4 __attribute__((ext_vector_type(4)));
typedef const __attribute__((address_space(1))) void gv_t;
typedef __attribute__((address_space(3))) void lv_t;

static __device__ __forceinline__ unsigned short f2bf(float f) {
  union { float ff; unsigned u; } x; x.ff = f;
  unsigned u = x.u + 0x7FFFu + ((x.u >> 16) & 1u);
  return (unsigned short)(u >> 16);
}
// pack two f32 -> bf16x2 dword (truncation; P in [0,1], 2% tol)
static __device__ __forceinline__ unsigned bftrunc2(float lo, float hi) {
  union { float ff; unsigned u; } a, b; a.ff = lo; b.ff = hi;
  return (a.u >> 16) | (b.u & 0xFFFF0000u);
}

__global__ void k_cvt(const float* __restrict__ in, unsigned short* __restrict__ out, int n4) {
  int i = blockIdx.x * 256 + threadIdx.x;
  if (i >= n4) return;
  f32x4 v = ((const f32x4*)in)[i];
  ushort4 o;
  o.x = f2bf(v[0]); o.y = f2bf(v[1]); o.z = f2bf(v[2]); o.w = f2bf(v[3]);
  ((ushort4*)out)[i] = o;
}

// C[M,N] = A[M,K] @ B[N,K]^T, bf16 in. MODE 0: bf16 out, cols<1024 *0.125 (Q prescale).
// MODE 1: f32 out + bias.
template<int MODE>
__global__ __launch_bounds__(256, 2) void k_gemm(
    const unsigned short* __restrict__ A, const unsigned short* __restrict__ B,
    void* __restrict__ Cout, const float* __restrict__ bias, int M, int N, int K)
{
  __shared__ unsigned short As[128 * 32];
  __shared__ unsigned short Bs[128 * 32];
  const int tid = threadIdx.x;
  const int w = tid >> 6, l = tid & 63;
  const int lane15 = l & 15, quad = l >> 4;
  const int m0 = blockIdx.y * 128, n0 = blockIdx.x * 128;
  const int wm = (w >> 1) * 64, wn = (w & 1) * 64;

  f32x4 acc[4][4];
#pragma unroll
  for (int i = 0; i < 4; i++)
#pragma unroll
    for (int j = 0; j < 4; j++) acc[i][j] = (f32x4){0.f, 0.f, 0.f, 0.f};

  // staging: issue = 16 rows x 32 k; lane l -> row l/4, slot chunk l%3.. (l&3).
  // XOR swizzle: slot c of row r holds global k-chunk c ^ ((r>>1)&3)  (chunk = 8 elems = 16B)
  const int srow = l >> 2;
  const int scol = ((l & 3) ^ ((l >> 3) & 3)) * 8;      // global k-chunk this lane fetches
  const int rchunk = (quad ^ ((lane15 >> 1) & 3)) * 8;  // LDS slot holding global chunk 'quad'

  const unsigned short* Arow0 = A + (size_t)(m0 + srow) * K + scol;
  const unsigned short* Brow0 = B + (size_t)(n0 + srow) * K + scol;

  for (int k0 = 0; k0 < K; k0 += 32) {
    __syncthreads();
#pragma unroll
    for (int i = 0; i < 2; i++) {
      int ji = w * 2 + i;
      __builtin_amdgcn_global_load_lds((gv_t*)(Arow0 + (size_t)(ji * 16) * K + k0),
                                       (lv_t*)&As[ji * 512], 16, 0, 0);
      __builtin_amdgcn_global_load_lds((gv_t*)(Brow0 + (size_t)(ji * 16) * K + k0),
                                       (lv_t*)&Bs[ji * 512], 16, 0, 0);
    }
    __syncthreads();
    bf16x8 af[4], bfr[4];
#pragma unroll
    for (int t = 0; t < 4; t++) {
      af[t]  = *(const bf16x8*)&As[(wm + t * 16 + lane15) * 32 + rchunk];
      bfr[t] = *(const bf16x8*)&Bs[(wn + t * 16 + lane15) * 32 + rchunk];
    }
#pragma unroll
    for (int i = 0; i < 4; i++)
#pragma unroll
      for (int j = 0; j < 4; j++)
        acc[i][j] = __builtin_amdgcn_mfma_f32_16x16x32_bf16(af[i], bfr[j], acc[i][j], 0, 0, 0);
  }

  if (MODE == 0) {
    unsigned short* Cp = (unsigned short*)Cout;
#pragma unroll
    for (int i = 0; i < 4; i++) {
      int rowb = m0 + wm + i * 16 + quad * 4;
#pragma unroll
      for (int j = 0; j < 4; j++) {
        int col = n0 + wn + j * 16 + lane15;
        float s = (col < 1024) ? 0.125f : 1.0f;
#pragma unroll
        for (int r = 0; r < 4; r++)
          Cp[(size_t)(rowb + r) * N + col] = f2bf(acc[i][j][r] * s);
      }
    }
  } else {
    float* Cp = (float*)Cout;
#pragma unroll
    for (int i = 0; i < 4; i++) {
      int rowb = m0 + wm + i * 16 + quad * 4;
#pragma unroll
      for (int j = 0; j < 4; j++) {
        int col = n0 + wn + j * 16 + lane15;
        float bv = bias[col];
#pragma unroll
        for (int r = 0; r < 4; r++)
          Cp[(size_t)(rowb + r) * N + col] = acc[i][j][r] + bv;
      }
    }
  }
}

// Flash-style causal attention. qkv [8192][3072] bf16 (Q prescaled by 0.125).
// Block: 4 waves; wave w owns q rows q0+16w..+15. Computes S^T[key][q] so softmax
// reductions are cross-quad shfl_xor; P^T(C-layout) -> A-operand via lane shuffles.
__global__ __launch_bounds__(256, 2) void k_attn(
    const unsigned short* __restrict__ qkv, unsigned short* __restrict__ attn_out)
{
  __shared__ unsigned short Ks[128 * 64];   // [key][d], xor-swizzled 16B chunks
  __shared__ unsigned short Vt[64 * 136];   // [d][key], padded stride 136
  const int tid = threadIdx.x;
  const int w = tid >> 6, l = tid & 63;
  const int lane15 = l & 15, quad = l >> 4;
  const int bh = blockIdx.y, b = bh >> 4, h = bh & 15;
  const int q0 = (int)(gridDim.x - 1 - blockIdx.x) * 64;  // heavy tiles first
  const size_t tokb = (size_t)b * SEQ;

  // Q b-frags: lane holds Q[q=lane15][d=quad*8+j]
  const unsigned short* qp = qkv + (tokb + q0 + w * 16 + lane15) * C3 + h * 64 + quad * 8;
  bf16x8 bq0 = *(const bf16x8*)qp;
  bf16x8 bq1 = *(const bf16x8*)(qp + 32);

  f32x4 O[4];
#pragma unroll
  for (int i = 0; i < 4; i++) O[i] = (f32x4){0.f, 0.f, 0.f, 0.f};
  float mrun = -1e30f, lrun = 0.f;

  const int qmy = q0 + w * 16 + lane15;         // this lane's q column
  const int nkt = (q0 + 64 + 127) >> 7;

  // K staging: issue = 8 rows x 8 chunks(16B); chunk slot c of row r holds global chunk c^(r&7)
  const int k_doff = ((l & 7) ^ ((l >> 3) & 7)) * 8;
  const int krow = l >> 3;
  const int vkey = tid >> 1, vdb = (tid & 1) * 32;
  const int rc0 = (quad ^ (lane15 & 7)) * 8;        // slot of global d-chunk quad
  const int rc1 = ((quad + 4) ^ (lane15 & 7)) * 8;  // slot of global d-chunk quad+4

  for (int kt = 0; kt < nkt; kt++) {
    const int k0 = kt * 128;
    __syncthreads();
#pragma unroll
    for (int i = 0; i < 4; i++) {
      int ji = w * 4 + i;
      const unsigned short* gk =
          qkv + (tokb + k0 + ji * 8 + krow) * C3 + C1 + h * 64 + k_doff;
      __builtin_amdgcn_global_load_lds((gv_t*)gk, (lv_t*)&Ks[ji * 512], 16, 0, 0);
    }
    {
      const unsigned short* gvp = qkv + (tokb + k0 + vkey) * C3 + 2 * C1 + h * 64 + vdb;
      short8 v0 = *(const short8*)(gvp);
      short8 v1 = *(const short8*)(gvp + 8);
      short8 v2 = *(const short8*)(gvp + 16);
      short8 v3 = *(const short8*)(gvp + 24);
      unsigned short* vt = &Vt[vkey];
#pragma unroll
      for (int j2 = 0; j2 < 8; j2++) {
        vt[(vdb + j2) * 136]      = (unsigned short)v0[j2];
        vt[(vdb + 8 + j2) * 136]  = (unsigned short)v1[j2];
        vt[(vdb + 16 + j2) * 136] = (unsigned short)v2[j2];
        vt[(vdb + 24 + j2) * 136] = (unsigned short)v3[j2];
      }
    }
    __syncthreads();

    // S^T[key][q]: A = K rows (M=key), B = Q (N=q). 8 row-tiles x (D=64 -> 2 ksteps)
    f32x4 st[8];
#pragma unroll
    for (int nt = 0; nt < 8; nt++) {
      const unsigned short* kr = &Ks[(nt * 16 + lane15) * 64];
      bf16x8 ak0 = *(const bf16x8*)(kr + rc0);
      bf16x8 ak1 = *(const bf16x8*)(kr + rc1);
      f32x4 z = (f32x4){0.f, 0.f, 0.f, 0.f};
      z = __builtin_amdgcn_mfma_f32_16x16x32_bf16(ak0, bq0, z, 0, 0, 0);
      z = __builtin_amdgcn_mfma_f32_16x16x32_bf16(ak1, bq1, z, 0, 0, 0);
      st[nt] = z;
    }

    if (k0 + 127 > q0) {  // tile crosses the diagonal -> mask
#pragma unroll
      for (int nt = 0; nt < 8; nt++)
#pragma unroll
        for (int r = 0; r < 4; r++) {
          int key = k0 + nt * 16 + quad * 4 + r;
          if (key > qmy) st[nt][r] = -1e30f;
        }
    }

    float vmax = -1e30f;
#pragma unroll
    for (int nt = 0; nt < 8; nt++)
#pragma unroll
      for (int r = 0; r < 4; r++) vmax = fmaxf(vmax, st[nt][r]);
    vmax = fmaxf(vmax, __shfl_xor(vmax, 16, 64));
    vmax = fmaxf(vmax, __shfl_xor(vmax, 32, 64));
    float mnew = fmaxf(mrun, vmax);
    float alpha = __expf(mrun - mnew);
    float psum = 0.f;
#pragma unroll
    for (int nt = 0; nt < 8; nt++)
#pragma unroll
      for (int r = 0; r < 4; r++) {
        float p = __expf(st[nt][r] - mnew);
        st[nt][r] = p;
        psum += p;
      }
    psum += __shfl_xor(psum, 16, 64);
    psum += __shfl_xor(psum, 32, 64);
    lrun = lrun * alpha + psum;
    mrun = mnew;

    // rescale O (row q' = quad*4+r; alpha for column q' lives in lane q')
#pragma unroll
    for (int r = 0; r < 4; r++) {
      float ar = __shfl(alpha, quad * 4 + r, 64);
#pragma unroll
      for (int dt = 0; dt < 4; dt++) O[dt][r] *= ar;
    }

    // pack P^T regs (r0,r1)/(r2,r3) as bf16x2 dwords
    unsigned pk0[8], pk1[8];
#pragma unroll
    for (int nt = 0; nt < 8; nt++) {
      pk0[nt] = bftrunc2(st[nt][0], st[nt][1]);
      pk1[nt] = bftrunc2(st[nt][2], st[nt][3]);
    }

    // P @ V: a-frag elem j = P[q=lane15][k=kw*32+quad*8+j], gathered by shfl from
    // src lane ((quad&1)*2 + (dw>>1))*16 + lane15, tile 2kw + (quad>>1), reg j&3.
#pragma unroll
    for (int kw = 0; kw < 4; kw++) {
      union { unsigned u[4]; bf16x8 v; } ap;
#pragma unroll
      for (int dw = 0; dw < 4; dw++) {
        int src = (((quad & 1) * 2 + (dw >> 1)) << 4) | lane15;
        unsigned s0 = (dw & 1) ? pk1[2 * kw] : pk0[2 * kw];
        unsigned s1 = (dw & 1) ? pk1[2 * kw + 1] : pk0[2 * kw + 1];
        unsigned vA = (unsigned)__shfl((int)s0, src, 64);
        unsigned vB = (unsigned)__shfl((int)s1, src, 64);
        ap.u[dw] = (quad >> 1) ? vB : vA;
      }
#pragma unroll
      for (int dt = 0; dt < 4; dt++) {
        bf16x8 bv = *(const bf16x8*)&Vt[(dt * 16 + lane15) * 136 + kw * 32 + quad * 8];
        O[dt] = __builtin_amdgcn_mfma_f32_16x16x32_bf16(ap.v, bv, O[dt], 0, 0, 0);
      }
    }
  }

  float linv = 1.f / lrun;
#pragma unroll
  for (int r = 0; r < 4; r++) {
    float li = __shfl(linv, quad * 4 + r, 64);
    size_t ob = (tokb + q0 + w * 16 + quad * 4 + r) * C1 + h * 64;
#pragma unroll
    for (int dt = 0; dt < 4; dt++)
      attn_out[ob + dt * 16 + lane15] = f2bf(O[dt][r] * li);
  }
}

extern "C" void kernel_launch(void* const* d_in, const int* in_sizes, int n_in,
                              void* d_out, int out_size, void* d_ws, size_t ws_size,
                              hipStream_t stream) {
  const float* x     = (const float*)d_in[0];
  const float* w_qkv = (const float*)d_in[1];
  const float* w_out = (const float*)d_in[2];
  const float* b_out = (const float*)d_in[3];
  float* out = (float*)d_out;

  // ws layout (bf16): xb 16MB | wqb 6MB | wob 2MB | qkv 48MB | attn 16MB  (~88MB)
  unsigned short* xb  = (unsigned short*)d_ws;
  unsigned short* wqb = xb  + (size_t)8192 * 1024;
  unsigned short* wob = wqb + (size_t)3072 * 1024;
  unsigned short* qkv = wob + (size_t)1024 * 1024;
  unsigned short* att = qkv + (size_t)8192 * 3072;

  k_cvt<<<8192, 256, 0, stream>>>(x, xb, 8192 * 1024 / 4);
  k_cvt<<<3072, 256, 0, stream>>>(w_qkv, wqb, 3072 * 1024 / 4);
  k_cvt<<<1024, 256, 0, stream>>>(w_out, wob, 1024 * 1024 / 4);
  k_gemm<0><<<dim3(24, 64), 256, 0, stream>>>(xb, wqb, (void*)qkv, nullptr, 8192, 3072, 1024);
  k_attn<<<dim3(32, 64), 256, 0, stream>>>(qkv, att);
  k_gemm<1><<<dim3(8, 64), 256, 0, stream>>>(att, wob, (void*)out, b_out, 8192, 1024, 1024);
}

// Round 2
// 319.516 us; speedup vs baseline: 1.0809x; 1.0809x over previous
//
#include <hip/hip_runtime.h>
#include <stdint.h>

#define SEQ 2048
#define C3 3072
#define C1 1024

typedef __bf16 bf16x8 __attribute__((ext_vector_type(8)));
typedef short short8 __attribute__((ext_vector_type(8)));
typedef float f32x4 __attribute__((ext_vector_type(4)));
typedef float f32x16 __attribute__((ext_vector_type(16)));
typedef const __attribute__((address_space(1))) void gv_t;
typedef __attribute__((address_space(3))) void lv_t;

static __device__ __forceinline__ unsigned short f2bf(float f) {
  union { float ff; unsigned u; } x; x.ff = f;
  unsigned u = x.u + 0x7FFFu + ((x.u >> 16) & 1u);
  return (unsigned short)(u >> 16);
}
static __device__ __forceinline__ unsigned rne2(float lo, float hi) {
  return (unsigned)f2bf(lo) | ((unsigned)f2bf(hi) << 16);
}
// truncation pack (P in [0,1], rel err <= 2^-8)
static __device__ __forceinline__ unsigned bftrunc2(float lo, float hi) {
  union { float ff; unsigned u; } a, b; a.ff = lo; b.ff = hi;
  return (a.u >> 16) | (b.u & 0xFFFF0000u);
}

__global__ void k_cvt(const float* __restrict__ in, unsigned short* __restrict__ out, int n4) {
  int i = blockIdx.x * 256 + threadIdx.x;
  if (i >= n4) return;
  f32x4 v = ((const f32x4*)in)[i];
  ushort4 o;
  o.x = f2bf(v[0]); o.y = f2bf(v[1]); o.z = f2bf(v[2]); o.w = f2bf(v[3]);
  ((ushort4*)out)[i] = o;
}

// C[M,N] = A[M,K] @ B[N,K]^T, bf16 in. MODE 0: bf16 out, cols<1024 scaled by
// 0.125*log2(e) (Q prescale for exp2-domain softmax). MODE 1: f32 out + bias.
template<int MODE>
__global__ __launch_bounds__(256, 2) void k_gemm(
    const unsigned short* __restrict__ A, const unsigned short* __restrict__ B,
    void* __restrict__ Cout, const float* __restrict__ bias, int M, int N, int K)
{
  __shared__ unsigned short As[128 * 32];
  __shared__ unsigned short Bs[128 * 32];
  const int tid = threadIdx.x;
  const int w = tid >> 6, l = tid & 63;
  const int lane15 = l & 15, quad = l >> 4;
  const int m0 = blockIdx.y * 128, n0 = blockIdx.x * 128;
  const int wm = (w >> 1) * 64, wn = (w & 1) * 64;

  f32x4 acc[4][4];
#pragma unroll
  for (int i = 0; i < 4; i++)
#pragma unroll
    for (int j = 0; j < 4; j++) acc[i][j] = (f32x4){0.f, 0.f, 0.f, 0.f};

  const int srow = l >> 2;
  const int scol = ((l & 3) ^ ((l >> 3) & 3)) * 8;
  const int rchunk = (quad ^ ((lane15 >> 1) & 3)) * 8;

  const unsigned short* Arow0 = A + (size_t)(m0 + srow) * K + scol;
  const unsigned short* Brow0 = B + (size_t)(n0 + srow) * K + scol;

  for (int k0 = 0; k0 < K; k0 += 32) {
    __syncthreads();
#pragma unroll
    for (int i = 0; i < 2; i++) {
      int ji = w * 2 + i;
      __builtin_amdgcn_global_load_lds((gv_t*)(Arow0 + (size_t)(ji * 16) * K + k0),
                                       (lv_t*)&As[ji * 512], 16, 0, 0);
      __builtin_amdgcn_global_load_lds((gv_t*)(Brow0 + (size_t)(ji * 16) * K + k0),
                                       (lv_t*)&Bs[ji * 512], 16, 0, 0);
    }
    __syncthreads();
    bf16x8 af[4], bfr[4];
#pragma unroll
    for (int t = 0; t < 4; t++) {
      af[t]  = *(const bf16x8*)&As[(wm + t * 16 + lane15) * 32 + rchunk];
      bfr[t] = *(const bf16x8*)&Bs[(wn + t * 16 + lane15) * 32 + rchunk];
    }
#pragma unroll
    for (int i = 0; i < 4; i++)
#pragma unroll
      for (int j = 0; j < 4; j++)
        acc[i][j] = __builtin_amdgcn_mfma_f32_16x16x32_bf16(af[i], bfr[j], acc[i][j], 0, 0, 0);
  }

  if (MODE == 0) {
    unsigned short* Cp = (unsigned short*)Cout;
#pragma unroll
    for (int i = 0; i < 4; i++) {
      int rowb = m0 + wm + i * 16 + quad * 4;
#pragma unroll
      for (int j = 0; j < 4; j++) {
        int col = n0 + wn + j * 16 + lane15;
        float s = (col < 1024) ? 0.18033688f : 1.0f;  // 0.125 * log2(e)
#pragma unroll
        for (int r = 0; r < 4; r++)
          Cp[(size_t)(rowb + r) * N + col] = f2bf(acc[i][j][r] * s);
      }
    }
  } else {
    float* Cp = (float*)Cout;
#pragma unroll
    for (int i = 0; i < 4; i++) {
      int rowb = m0 + wm + i * 16 + quad * 4;
#pragma unroll
      for (int j = 0; j < 4; j++) {
        int col = n0 + wn + j * 16 + lane15;
        float bv = bias[col];
#pragma unroll
        for (int r = 0; r < 4; r++)
          Cp[(size_t)(rowb + r) * N + col] = acc[i][j][r] + bv;
      }
    }
  }
}

// V transpose: qkv V-block [tok][h*64+d] -> vT[(bh*64+d)][tok]
__global__ void k_vt(const unsigned short* __restrict__ qkv, unsigned short* __restrict__ vT) {
  __shared__ unsigned short T[64 * 65];
  int t = threadIdx.x;
  int bh = blockIdx.y, b = bh >> 4, h = bh & 15;
  int t0 = blockIdx.x * 64;
  int tokl = t >> 2, dl = (t & 3) * 16;
  const unsigned short* g = qkv + (size_t)(b * SEQ + t0 + tokl) * C3 + 2 * C1 + h * 64 + dl;
  short8 v0 = *(const short8*)g;
  short8 v1 = *(const short8*)(g + 8);
#pragma unroll
  for (int j = 0; j < 8; j++) {
    T[(dl + j) * 65 + tokl]     = (unsigned short)v0[j];
    T[(dl + 8 + j) * 65 + tokl] = (unsigned short)v1[j];
  }
  __syncthreads();
  int d2 = t >> 2, tk = (t & 3) * 16;
  union { unsigned short s[16]; short8 v[2]; } o;
#pragma unroll
  for (int j = 0; j < 16; j++) o.s[j] = T[d2 * 65 + tk + j];
  unsigned short* og = vT + ((size_t)bh * 64 + d2) * SEQ + t0 + tk;
  *(short8*)og = o.v[0];
  *(short8*)(og + 8) = o.v[1];
}

// Flash attention, 32x32x16 MFMA. Block = 4 waves x 32 q = 128 q.
// S^T[key][q] (q = lane&31): softmax in-lane; O^T = V^T @ P^T accumulated in
// C-layout; P^T C->B transform = 2 shfl_xor(32) + 6 selects per 16-key kstep.
// K and V^T double-buffered via global_load_lds (XOR-swizzled 16B chunks).
__global__ __launch_bounds__(256, 2) void k_attn(
    const unsigned short* __restrict__ qkv, const unsigned short* __restrict__ vT,
    unsigned short* __restrict__ att)
{
  __shared__ unsigned short buf[2][16384];  // [Ks 128x64 | Vt 64x128] x2
  const int tid = threadIdx.x;
  const int w = tid >> 6, l = tid & 63;
  const int l31 = l & 31, hl = l >> 5;
  const int bh = blockIdx.y, b = bh >> 4, h = bh & 15;
  const int qt = (int)(gridDim.x - 1 - blockIdx.x);  // heavy tiles first
  const int q0 = qt * 128;
  const int nkt = qt + 1;
  const size_t tokb = (size_t)b * SEQ;
  const int qmy = q0 + w * 32 + l31;

  // Q B-frags (global, once): B[k=d][n=q], k = hl*8+j within kstep
  bf16x8 qf[4];
  {
    const unsigned short* qp = qkv + (tokb + q0 + w * 32 + l31) * C3 + h * 64 + hl * 8;
#pragma unroll
    for (int ks = 0; ks < 4; ks++) qf[ks] = *(const bf16x8*)(qp + ks * 16);
  }

  f32x16 O[2];
#pragma unroll
  for (int i = 0; i < 16; i++) { O[0][i] = 0.f; O[1][i] = 0.f; }
  float mrun = -1e30f, lrun = 0.f;

  // staging lane constants
  const int krow_l = l >> 3, kslot = l & 7;
  const int vrow_l = l >> 4, vslot = l & 15;

  auto stage = [&](int kt, int p) {
    const int k0s = kt << 7;
    unsigned short* Kb = &buf[p][0];
    unsigned short* Vb = &buf[p][8192];
#pragma unroll
    for (int i = 0; i < 4; i++) {
      int rb = (w * 4 + i) * 8;
      int row = rb + krow_l;
      int ck = kslot ^ (row & 7);
      const unsigned short* g = qkv + (tokb + k0s + row) * C3 + C1 + h * 64 + ck * 8;
      __builtin_amdgcn_global_load_lds((gv_t*)g, (lv_t*)&Kb[rb * 64], 16, 0, 0);
    }
#pragma unroll
    for (int i = 0; i < 4; i++) {
      int rb = (w * 4 + i) * 4;
      int row = rb + vrow_l;
      int ck = vslot ^ (row & 15);
      const unsigned short* g = vT + ((size_t)bh * 64 + row) * SEQ + k0s + ck * 8;
      __builtin_amdgcn_global_load_lds((gv_t*)g, (lv_t*)&Vb[rb * 128], 16, 0, 0);
    }
  };

  stage(0, 0);

  for (int kt = 0; kt < nkt; kt++) {
    const int p = kt & 1;
    const int k0 = kt << 7;
    __syncthreads();               // buf[p] ready; buf[p^1] free
    if (kt + 1 < nkt) stage(kt + 1, p ^ 1);

    const unsigned short* Kb = &buf[p][0];
    const unsigned short* Vb = &buf[p][8192];

    // S^T = K @ Q^T : C[key][q]
    f32x16 st[4];
#pragma unroll
    for (int mt = 0; mt < 4; mt++) {
#pragma unroll
      for (int i = 0; i < 16; i++) st[mt][i] = 0.f;
      int row = mt * 32 + l31;
      const unsigned short* kr = &Kb[row * 64];
#pragma unroll
      for (int ks = 0; ks < 4; ks++) {
        bf16x8 a = *(const bf16x8*)&kr[((((ks << 1) | hl)) ^ (row & 7)) * 8];
        st[mt] = __builtin_amdgcn_mfma_f32_32x32x16_bf16(a, qf[ks], st[mt], 0, 0, 0);
      }
    }

    if (kt == nkt - 1) {  // diagonal tile: causal mask
#pragma unroll
      for (int mt = 0; mt < 4; mt++)
#pragma unroll
        for (int r = 0; r < 16; r++) {
          int key = k0 + mt * 32 + (r & 3) + ((r >> 2) << 3) + (hl << 2);
          if (key > qmy) st[mt][r] = -1e30f;
        }
    }

    float vmax = -1e30f;
#pragma unroll
    for (int mt = 0; mt < 4; mt++)
#pragma unroll
      for (int r = 0; r < 16; r++) vmax = fmaxf(vmax, st[mt][r]);
    vmax = fmaxf(vmax, __shfl_xor(vmax, 32, 64));
    float mnew = fmaxf(mrun, vmax);
    float alpha = exp2f(mrun - mnew);

    float psum = 0.f;
    unsigned pk[4][8];
#pragma unroll
    for (int mt = 0; mt < 4; mt++) {
#pragma unroll
      for (int r = 0; r < 16; r++) {
        float pv = exp2f(st[mt][r] - mnew);
        st[mt][r] = pv;
        psum += pv;
      }
#pragma unroll
      for (int k2 = 0; k2 < 8; k2++)
        pk[mt][k2] = bftrunc2(st[mt][2 * k2], st[mt][2 * k2 + 1]);
    }
    psum += __shfl_xor(psum, 32, 64);
    lrun = lrun * alpha + psum;
    mrun = mnew;

#pragma unroll
    for (int i = 0; i < 16; i++) { O[0][i] *= alpha; O[1][i] *= alpha; }

    // O^T += V^T @ P^T
#pragma unroll
    for (int ks = 0; ks < 8; ks++) {
      int mt = ks >> 1, e = ks & 1;
      unsigned pA0 = pk[mt][4 * e], pA1 = pk[mt][4 * e + 1];
      unsigned pB0 = pk[mt][4 * e + 2], pB1 = pk[mt][4 * e + 3];
      unsigned w0 = hl ? pA0 : pB0, w1 = hl ? pA1 : pB1;
      unsigned r0 = (unsigned)__shfl_xor((int)w0, 32, 64);
      unsigned r1 = (unsigned)__shfl_xor((int)w1, 32, 64);
      unsigned s0 = hl ? pB0 : pA0, s1 = hl ? pB1 : pA1;
      union { unsigned u[4]; bf16x8 v; } Bf;
      Bf.u[0] = hl ? r0 : s0; Bf.u[1] = hl ? r1 : s1;
      Bf.u[2] = hl ? s0 : r0; Bf.u[3] = hl ? s1 : r1;
#pragma unroll
      for (int dt = 0; dt < 2; dt++) {
        int row = dt * 32 + l31;
        bf16x8 a = *(const bf16x8*)&Vb[row * 128 + (((2 * ks + hl)) ^ (row & 15)) * 8];
        O[dt] = __builtin_amdgcn_mfma_f32_32x32x16_bf16(a, Bf.v, O[dt], 0, 0, 0);
      }
    }
  }

  // epilogue: O^T (C-layout) -> LDS [q][d] -> coalesced bf16 store
  __syncthreads();  // all waves done reading buf before overlay
  float linv = 1.f / lrun;
  unsigned* epi32 = (unsigned*)&buf[0][0];
  const int base = w * 2304 + l31 * 72;
#pragma unroll
  for (int dt = 0; dt < 2; dt++)
#pragma unroll
    for (int c = 0; c < 4; c++) {
      int d0 = dt * 32 + c * 8 + hl * 4;
      epi32[(base + d0) >> 1]     = rne2(O[dt][4 * c] * linv, O[dt][4 * c + 1] * linv);
      epi32[(base + d0 + 2) >> 1] = rne2(O[dt][4 * c + 2] * linv, O[dt][4 * c + 3] * linv);
    }
  __builtin_amdgcn_s_waitcnt(0);  // lgkm drain before cross-lane read (same wave)
  {
    int q = l >> 1, hf = l & 1;
    const unsigned short* ep = &buf[0][w * 2304 + q * 72 + hf * 32];
    unsigned short* og = att + (tokb + q0 + w * 32 + q) * C1 + h * 64 + hf * 32;
#pragma unroll
    for (int c2 = 0; c2 < 4; c2++)
      *(bf16x8*)(og + c2 * 8) = *(const bf16x8*)&ep[c2 * 8];
  }
}

extern "C" void kernel_launch(void* const* d_in, const int* in_sizes, int n_in,
                              void* d_out, int out_size, void* d_ws, size_t ws_size,
                              hipStream_t stream) {
  const float* x     = (const float*)d_in[0];
  const float* w_qkv = (const float*)d_in[1];
  const float* w_out = (const float*)d_in[2];
  const float* b_out = (const float*)d_in[3];
  float* out = (float*)d_out;

  // ws layout (bf16 elems): xb 8.39M | wqb 3.15M | wob 1.05M | qkv 25.2M | att 8.39M | vT 8.39M
  unsigned short* xb  = (unsigned short*)d_ws;
  unsigned short* wqb = xb  + (size_t)8192 * 1024;
  unsigned short* wob = wqb + (size_t)3072 * 1024;
  unsigned short* qkv = wob + (size_t)1024 * 1024;
  unsigned short* att = qkv + (size_t)8192 * 3072;
  unsigned short* vT  = att + (size_t)8192 * 1024;

  k_cvt<<<8192, 256, 0, stream>>>(x, xb, 8192 * 1024 / 4);
  k_cvt<<<3072, 256, 0, stream>>>(w_qkv, wqb, 3072 * 1024 / 4);
  k_cvt<<<1024, 256, 0, stream>>>(w_out, wob, 1024 * 1024 / 4);
  k_gemm<0><<<dim3(24, 64), 256, 0, stream>>>(xb, wqb, (void*)qkv, nullptr, 8192, 3072, 1024);
  k_vt<<<dim3(32, 64), 256, 0, stream>>>(qkv, vT);
  k_attn<<<dim3(16, 64), 256, 0, stream>>>(qkv, vT, att);
  k_gemm<1><<<dim3(8, 64), 256, 0, stream>>>(att, wob, (void*)out, b_out, 8192, 1024, 1024);
}